// Round 1
// baseline (63.793 us; speedup 1.0000x reference)
//
#include <hip/hip_runtime.h>
#include <stdint.h>

#define BATCH   32768
#define NBITS   512
#define NWORDS  512          // BATCH / 64
#define NPAIRS  130816       // 512*511/2
#define WCHUNK  64

typedef unsigned long long u64;

// ---------------------------------------------------------------------------
// Pass 1: bit-pack. packed[w*NBITS + col] = 64-bit mask of rows w*64..w*64+63
// for column col (bit set where bits > 0, i.e. b==1).
// Each wave handles (column-half cg, word w): lane reads float4 (4 columns),
// 64 coalesced 1KB wave-loads.
// ---------------------------------------------------------------------------
__global__ __launch_bounds__(256) void pack_kernel(const float* __restrict__ bits,
                                                   u64* __restrict__ packed) {
    const int wv   = threadIdx.x >> 6;
    const int lane = threadIdx.x & 63;
    const int gw   = blockIdx.x * 4 + wv;     // 0..1023
    const int cg   = gw & 1;                  // column half (0..1)
    const int w    = gw >> 1;                 // word 0..511
    const int c0   = cg * 256 + lane * 4;

    u64 m0 = 0, m1 = 0, m2 = 0, m3 = 0;
    const float* base = bits + (size_t)w * 64 * NBITS + c0;
#pragma unroll 16
    for (int r = 0; r < 64; ++r) {
        float4 v = *reinterpret_cast<const float4*>(base + (size_t)r * NBITS);
        const u64 b = 1ull << r;
        if (v.x > 0.0f) m0 |= b;
        if (v.y > 0.0f) m1 |= b;
        if (v.z > 0.0f) m2 |= b;
        if (v.w > 0.0f) m3 |= b;
    }
    u64* dst = packed + (size_t)w * NBITS + c0;
    dst[0] = m0; dst[1] = m1; dst[2] = m2; dst[3] = m3;
}

// ---------------------------------------------------------------------------
// Pass 2: Gram matrix C[i*512+j] = popcount(col_i AND col_j), lower triangle
// incl. diagonal (C[i][i] = c1[i]). 136 blocks = 16x16 triangle of 32x32
// tiles; LDS-staged word chunks; 2x2 register tile per thread.
// ---------------------------------------------------------------------------
__global__ __launch_bounds__(256) void gram_kernel(const u64* __restrict__ packed,
                                                   int* __restrict__ C) {
    __shared__ u64 ldsI[WCHUNK][32];
    __shared__ u64 ldsJ[WCHUNK][32];

    const int k = blockIdx.x;
    int bi = (int)((sqrtf(8.0f * (float)k + 1.0f) - 1.0f) * 0.5f);
    while ((bi + 1) * (bi + 2) / 2 <= k) ++bi;
    while (bi * (bi + 1) / 2 > k) --bi;
    const int bj = k - bi * (bi + 1) / 2;

    const int i0 = bi * 32, j0 = bj * 32;
    const int ti2 = (threadIdx.x & 15) * 2;   // i offset within tile (even)
    const int tj2 = (threadIdx.x >> 4) * 2;   // j offset within tile (even)

    int acc00 = 0, acc01 = 0, acc10 = 0, acc11 = 0;

    for (int w0 = 0; w0 < NWORDS; w0 += WCHUNK) {
        __syncthreads();
        // load WCHUNK*32 u64 for each side; 32 threads per word row -> coalesced
        for (int s = threadIdx.x; s < WCHUNK * 32; s += 256) {
            const int wo = s >> 5, col = s & 31;
            ldsI[wo][col] = packed[(size_t)(w0 + wo) * NBITS + i0 + col];
            ldsJ[wo][col] = packed[(size_t)(w0 + wo) * NBITS + j0 + col];
        }
        __syncthreads();
#pragma unroll 4
        for (int w = 0; w < WCHUNK; ++w) {
            const u64 a0 = ldsI[w][ti2], a1 = ldsI[w][ti2 + 1];
            const u64 b0 = ldsJ[w][tj2], b1 = ldsJ[w][tj2 + 1];
            acc00 += __popcll(a0 & b0);
            acc01 += __popcll(a0 & b1);
            acc10 += __popcll(a1 & b0);
            acc11 += __popcll(a1 & b1);
        }
    }

    const int i = i0 + ti2, j = j0 + tj2;
    C[(size_t)i * NBITS + j]           = acc00;
    C[(size_t)i * NBITS + j + 1]       = acc01;
    C[(size_t)(i + 1) * NBITS + j]     = acc10;
    C[(size_t)(i + 1) * NBITS + j + 1] = acc11;
}

// ---------------------------------------------------------------------------
// Pass 3: per-pair MI terms (f64, exact integer counts), deterministic
// block reduction -> per-block partials.
// ---------------------------------------------------------------------------
__global__ __launch_bounds__(256) void mi_kernel(const int* __restrict__ C,
                                                 double* __restrict__ bsum,
                                                 int* __restrict__ bcnt) {
    const double invB = 1.0 / (double)BATCH;
    double lsum = 0.0;
    int lcnt = 0;

    for (int k = blockIdx.x * 256 + threadIdx.x; k < NPAIRS; k += gridDim.x * 256) {
        // decode pair: k = i*(i-1)/2 + j, i > j
        int i = (int)((1.0 + sqrt(1.0 + 8.0 * (double)k)) * 0.5);
        while ((i * (i - 1)) / 2 > k) --i;
        while (((i + 1) * i) / 2 <= k) ++i;
        const int j = k - (i * (i - 1)) / 2;

        const int n11 = C[i * NBITS + j];
        const int ci  = C[i * NBITS + i];
        const int cj  = C[j * NBITS + j];
        const int n10 = ci - n11;
        const int n01 = cj - n11;
        const int n00 = BATCH - ci - cj + n11;

        const int pim[2] = {BATCH - ci, ci};
        const int pjn[2] = {BATCH - cj, cj};
        const int nmn[2][2] = {{n00, n01}, {n10, n11}};

#pragma unroll
        for (int m = 0; m < 2; ++m)
#pragma unroll
            for (int n = 0; n < 2; ++n) {
                const int c_mn = nmn[m][n];
                if (c_mn > 0 && pim[m] > 0 && pjn[n] > 0) {
                    const double p = (double)c_mn * invB;
                    const double ratio = ((double)c_mn * (double)BATCH) /
                                         ((double)pim[m] * (double)pjn[n]);
                    lsum += p * log(ratio);
                    ++lcnt;
                }
            }
    }

    __shared__ double ssum[256];
    __shared__ int scnt[256];
    ssum[threadIdx.x] = lsum;
    scnt[threadIdx.x] = lcnt;
    __syncthreads();
    for (int off = 128; off > 0; off >>= 1) {
        if (threadIdx.x < off) {
            ssum[threadIdx.x] += ssum[threadIdx.x + off];
            scnt[threadIdx.x] += scnt[threadIdx.x + off];
        }
        __syncthreads();
    }
    if (threadIdx.x == 0) { bsum[blockIdx.x] = ssum[0]; bcnt[blockIdx.x] = scnt[0]; }
}

// ---------------------------------------------------------------------------
// Pass 4: final deterministic reduce, out = sum / cnt.
// ---------------------------------------------------------------------------
__global__ __launch_bounds__(256) void final_kernel(const double* __restrict__ bsum,
                                                    const int* __restrict__ bcnt,
                                                    float* __restrict__ out,
                                                    int nblocks) {
    __shared__ double ssum[256];
    __shared__ int scnt[256];
    double s = 0.0; int c = 0;
    for (int k = threadIdx.x; k < nblocks; k += 256) { s += bsum[k]; c += bcnt[k]; }
    ssum[threadIdx.x] = s;
    scnt[threadIdx.x] = c;
    __syncthreads();
    for (int off = 128; off > 0; off >>= 1) {
        if (threadIdx.x < off) {
            ssum[threadIdx.x] += ssum[threadIdx.x + off];
            scnt[threadIdx.x] += scnt[threadIdx.x + off];
        }
        __syncthreads();
    }
    if (threadIdx.x == 0) out[0] = (float)(ssum[0] / (double)scnt[0]);
}

// ---------------------------------------------------------------------------
extern "C" void kernel_launch(void* const* d_in, const int* in_sizes, int n_in,
                              void* d_out, int out_size, void* d_ws, size_t ws_size,
                              hipStream_t stream) {
    const float* bits = (const float*)d_in[0];
    char* ws = (char*)d_ws;
    u64*    packed = (u64*)ws;                        // 2 MB
    int*    C      = (int*)(ws + 2097152);            // 1 MB
    double* bsum   = (double*)(ws + 3145728);         // 2 KB
    int*    bcnt   = (int*)(ws + 3147776);            // 1 KB

    pack_kernel<<<256, 256, 0, stream>>>(bits, packed);
    gram_kernel<<<136, 256, 0, stream>>>(packed, C);
    mi_kernel<<<256, 256, 0, stream>>>(C, bsum, bcnt);
    final_kernel<<<1, 256, 0, stream>>>(bsum, bcnt, (float*)d_out, 256);
}

// Round 2
// 51.592 us; speedup vs baseline: 1.2365x; 1.2365x over previous
//
#include <hip/hip_runtime.h>
#include <stdint.h>

#define BATCH   32768
#define NBITS   512
#define NWORDS  512          // BATCH / 64
#define NPAIRS  130816       // 512*511/2
#define NSLICE  7            // K-split for gram (36*7 = 252 blocks ~ 1/CU)
#define CH      37           // LDS word-chunk (2*37*64*8 = 37.9 KB)

typedef unsigned long long u64;

// ---------------------------------------------------------------------------
// Pass 1: bit-pack + zero C + build f64 log table.
// packed[w*NBITS + col] = 64-bit mask of rows w*64..w*64+63 for column col.
// ---------------------------------------------------------------------------
__global__ __launch_bounds__(256) void pack_kernel(const float* __restrict__ bits,
                                                   u64* __restrict__ packed,
                                                   int* __restrict__ C,
                                                   double* __restrict__ lg) {
    const int gid = blockIdx.x * 256 + threadIdx.x;   // 0..65535

    // zero the Gram accumulator (262144 ints; 4 per thread, int4 store)
    reinterpret_cast<int4*>(C)[gid] = make_int4(0, 0, 0, 0);

    // f64 log table for the MI epilogue (args are integers 0..32768)
    if (gid <= BATCH) lg[gid] = (gid > 0) ? log((double)gid) : 0.0;

    const int wv   = threadIdx.x >> 6;
    const int lane = threadIdx.x & 63;
    const int gw   = blockIdx.x * 4 + wv;     // 0..1023
    const int cg   = gw & 1;                  // column half (0..1)
    const int w    = gw >> 1;                 // word 0..511
    const int c0   = cg * 256 + lane * 4;

    u64 m0 = 0, m1 = 0, m2 = 0, m3 = 0;
    const float* base = bits + (size_t)w * 64 * NBITS + c0;
#pragma unroll 16
    for (int r = 0; r < 64; ++r) {
        float4 v = *reinterpret_cast<const float4*>(base + (size_t)r * NBITS);
        const u64 b = 1ull << r;
        if (v.x > 0.0f) m0 |= b;
        if (v.y > 0.0f) m1 |= b;
        if (v.z > 0.0f) m2 |= b;
        if (v.w > 0.0f) m3 |= b;
    }
    u64* dst = packed + (size_t)w * NBITS + c0;
    dst[0] = m0; dst[1] = m1; dst[2] = m2; dst[3] = m3;
}

// ---------------------------------------------------------------------------
// Pass 2: Gram matrix C[i*512+j] += popcount(col_i AND col_j) over this
// block's K-slice. 36 tile-blocks (64x64, 8x8 triangle) x 7 K-slices = 252
// blocks (~1 per CU). 4x4 register tile per thread with interleaved columns
// {2t, 2t+1, 2t+32, 2t+33}: b128 LDS reads land on 2-way-aliased banks (free).
// Integer atomicAdd combine (exact + deterministic).
// ---------------------------------------------------------------------------
__global__ __launch_bounds__(256) void gram_kernel(const u64* __restrict__ packed,
                                                   int* __restrict__ C) {
    __shared__ u64 ldsI[CH][64];
    __shared__ u64 ldsJ[CH][64];

    const int s = blockIdx.x % NSLICE;      // K-slice
    const int t = blockIdx.x / NSLICE;      // tile 0..35
    int bi = (int)((sqrtf(8.0f * (float)t + 1.0f) - 1.0f) * 0.5f);
    while ((bi + 1) * (bi + 2) / 2 <= t) ++bi;
    while (bi * (bi + 1) / 2 > t) --bi;
    const int bj = t - bi * (bi + 1) / 2;

    const int i0 = bi * 64, j0 = bj * 64;
    const int w0 = (s * NWORDS) / NSLICE;
    const int w1 = ((s + 1) * NWORDS) / NSLICE;
    const bool diag = (bi == bj);

    const int ti2 = (threadIdx.x & 15) * 2;   // i-col base (even)
    const int tj2 = (threadIdx.x >> 4) * 2;   // j-col base (even)

    int acc[4][4] = {};

    for (int wb = w0; wb < w1; wb += CH) {
        const int nw = min(CH, w1 - wb);
        __syncthreads();
        for (int q = threadIdx.x; q < nw * 32; q += 256) {
            const int wo = q >> 5, cp = (q & 31) * 2;
            const size_t g = (size_t)(wb + wo) * NBITS;
            *reinterpret_cast<ulonglong2*>(&ldsI[wo][cp]) =
                *reinterpret_cast<const ulonglong2*>(&packed[g + i0 + cp]);
            if (!diag)
                *reinterpret_cast<ulonglong2*>(&ldsJ[wo][cp]) =
                    *reinterpret_cast<const ulonglong2*>(&packed[g + j0 + cp]);
        }
        __syncthreads();
        const u64 (*BJ)[64] = diag ? ldsI : ldsJ;
#pragma unroll 2
        for (int w = 0; w < nw; ++w) {
            const u64 a0 = ldsI[w][ti2],      a1 = ldsI[w][ti2 + 1];
            const u64 a2 = ldsI[w][ti2 + 32], a3 = ldsI[w][ti2 + 33];
            const u64 b0 = BJ[w][tj2],        b1 = BJ[w][tj2 + 1];
            const u64 b2 = BJ[w][tj2 + 32],   b3 = BJ[w][tj2 + 33];
            acc[0][0] += __popcll(a0 & b0); acc[0][1] += __popcll(a0 & b1);
            acc[0][2] += __popcll(a0 & b2); acc[0][3] += __popcll(a0 & b3);
            acc[1][0] += __popcll(a1 & b0); acc[1][1] += __popcll(a1 & b1);
            acc[1][2] += __popcll(a1 & b2); acc[1][3] += __popcll(a1 & b3);
            acc[2][0] += __popcll(a2 & b0); acc[2][1] += __popcll(a2 & b1);
            acc[2][2] += __popcll(a2 & b2); acc[2][3] += __popcll(a2 & b3);
            acc[3][0] += __popcll(a3 & b0); acc[3][1] += __popcll(a3 & b1);
            acc[3][2] += __popcll(a3 & b2); acc[3][3] += __popcll(a3 & b3);
        }
    }

    const int ic[4] = {i0 + ti2, i0 + ti2 + 1, i0 + ti2 + 32, i0 + ti2 + 33};
    const int jc[4] = {j0 + tj2, j0 + tj2 + 1, j0 + tj2 + 32, j0 + tj2 + 33};
#pragma unroll
    for (int a = 0; a < 4; ++a)
#pragma unroll
        for (int b = 0; b < 4; ++b)
            atomicAdd(&C[(size_t)ic[a] * NBITS + jc[b]], acc[a][b]);
}

// ---------------------------------------------------------------------------
// Pass 3: per-pair MI terms via log table (exact integer counts),
// deterministic block reduction -> per-block partials. 1 pair per thread.
// ---------------------------------------------------------------------------
__global__ __launch_bounds__(256) void mi_kernel(const int* __restrict__ C,
                                                 const double* __restrict__ lg,
                                                 double* __restrict__ bsum,
                                                 int* __restrict__ bcnt) {
    const double invB = 1.0 / (double)BATCH;
    double lsum = 0.0;
    int lcnt = 0;

    const int k = blockIdx.x * 256 + threadIdx.x;
    if (k < NPAIRS) {
        // decode pair: k = i*(i-1)/2 + j, i > j
        int i = (int)((1.0 + sqrt(1.0 + 8.0 * (double)k)) * 0.5);
        while ((i * (i - 1)) / 2 > k) --i;
        while (((i + 1) * i) / 2 <= k) ++i;
        const int j = k - (i * (i - 1)) / 2;

        const int n11 = C[i * NBITS + j];
        const int ci  = C[i * NBITS + i];
        const int cj  = C[j * NBITS + j];

        const int pim[2] = {BATCH - ci, ci};
        const int pjn[2] = {BATCH - cj, cj};
        const int nmn[2][2] = {{BATCH - ci - cj + n11, cj - n11},
                               {ci - n11, n11}};
        const double lgB = lg[BATCH];

#pragma unroll
        for (int m = 0; m < 2; ++m)
#pragma unroll
            for (int n = 0; n < 2; ++n) {
                const int c_mn = nmn[m][n];
                if (c_mn > 0 && pim[m] > 0 && pjn[n] > 0) {
                    lsum += (double)c_mn * invB *
                            (lg[c_mn] + lgB - lg[pim[m]] - lg[pjn[n]]);
                    ++lcnt;
                }
            }
    }

    __shared__ double ssum[256];
    __shared__ int scnt[256];
    ssum[threadIdx.x] = lsum;
    scnt[threadIdx.x] = lcnt;
    __syncthreads();
    for (int off = 128; off > 0; off >>= 1) {
        if (threadIdx.x < off) {
            ssum[threadIdx.x] += ssum[threadIdx.x + off];
            scnt[threadIdx.x] += scnt[threadIdx.x + off];
        }
        __syncthreads();
    }
    if (threadIdx.x == 0) { bsum[blockIdx.x] = ssum[0]; bcnt[blockIdx.x] = scnt[0]; }
}

// ---------------------------------------------------------------------------
// Pass 4: final deterministic reduce, out = sum / cnt.
// ---------------------------------------------------------------------------
__global__ __launch_bounds__(256) void final_kernel(const double* __restrict__ bsum,
                                                    const int* __restrict__ bcnt,
                                                    float* __restrict__ out,
                                                    int nblocks) {
    __shared__ double ssum[256];
    __shared__ int scnt[256];
    double s = 0.0; int c = 0;
    for (int k = threadIdx.x; k < nblocks; k += 256) { s += bsum[k]; c += bcnt[k]; }
    ssum[threadIdx.x] = s;
    scnt[threadIdx.x] = c;
    __syncthreads();
    for (int off = 128; off > 0; off >>= 1) {
        if (threadIdx.x < off) {
            ssum[threadIdx.x] += ssum[threadIdx.x + off];
            scnt[threadIdx.x] += scnt[threadIdx.x + off];
        }
        __syncthreads();
    }
    if (threadIdx.x == 0) out[0] = (float)(ssum[0] / (double)scnt[0]);
}

// ---------------------------------------------------------------------------
extern "C" void kernel_launch(void* const* d_in, const int* in_sizes, int n_in,
                              void* d_out, int out_size, void* d_ws, size_t ws_size,
                              hipStream_t stream) {
    const float* bits = (const float*)d_in[0];
    char* ws = (char*)d_ws;
    u64*    packed = (u64*)ws;                        // 2 MB
    int*    C      = (int*)(ws + (2u << 20));         // 1 MB
    double* lg     = (double*)(ws + (3u << 20));      // 256 KB + 8 B
    double* bsum   = (double*)(ws + (3u << 20) + 524288);  // 4 KB
    int*    bcnt   = (int*)(ws + (3u << 20) + 524288 + 8192);

    pack_kernel<<<256, 256, 0, stream>>>(bits, packed, C, lg);
    gram_kernel<<<36 * NSLICE, 256, 0, stream>>>(packed, C);
    mi_kernel<<<512, 256, 0, stream>>>(C, lg, bsum, bcnt);
    final_kernel<<<1, 256, 0, stream>>>(bsum, bcnt, (float*)d_out, 512);
}